// Round 1
// baseline (30506.479 us; speedup 1.0000x reference)
//
#include <hip/hip_runtime.h>
#include <hip/hip_fp16.h>

#define T_STEPS 2048
#define BATCH   32
#define DIM     1024

typedef _Float16 half2_t __attribute__((ext_vector_type(2)));
typedef _Float16 f16x8  __attribute__((ext_vector_type(8)));
typedef float    f32x4  __attribute__((ext_vector_type(4)));

__device__ __forceinline__ float fdot2(unsigned a, unsigned b, float c) {
#if defined(__has_builtin) && __has_builtin(__builtin_amdgcn_fdot2)
    return __builtin_amdgcn_fdot2(__builtin_bit_cast(half2_t, a),
                                  __builtin_bit_cast(half2_t, b), c, false);
#else
    float d;
    asm("v_dot2_f32_f16 %0, %1, %2, %3" : "=v"(d) : "v"(a), "v"(b), "v"(c));
    return d;
#endif
}

// ---------------------------------------------------------------------------
// Kernel 1: repack W_h (fp32 [k][n]) -> f16, layout [kb][n][8] where k = 8*kb+i.
// A thread owning output column n then reads 8 consecutive k as one dwordx4,
// and lanes with consecutive n are fully coalesced (16B * 64 lanes contiguous).
// ---------------------------------------------------------------------------
__global__ void conv_wh(const float* __restrict__ Wh, _Float16* __restrict__ Wh2) {
    const int idx = blockIdx.x * blockDim.x + threadIdx.x;   // 0 .. DIM*DIM-1
    const int k = idx >> 10;
    const int n = idx & (DIM - 1);
    Wh2[((size_t)(k >> 3) * DIM + n) * 8 + (k & 7)] = (_Float16)Wh[idx];
}

// ---------------------------------------------------------------------------
// Kernel 2: xW = x @ W_x + (bias added in epilogue... bias applied here), f16
// MFMA 16x16x32, 128x128 tile, BK=32, fp32 inputs converted during staging.
// Output written fp32 into the h_all[1:] region of d_out (later overwritten
// in-place, element-exact, by the recurrence).
// ---------------------------------------------------------------------------
#define BM 128
#define BN 128
#define BK 32
#define LDT 40   // padded leading dim (halves): 80B row stride, 16B aligned

__global__ __launch_bounds__(256) void gemm_xw(
    const float* __restrict__ X,     // [M=T*B][DIM]
    const float* __restrict__ Wx,    // [DIM][DIM]
    const float* __restrict__ bias,  // [DIM]
    float* __restrict__ out)         // [M][DIM] == h_all + BATCH*DIM
{
    __shared__ _Float16 As[BM][LDT];
    __shared__ _Float16 Bs[BN][LDT];   // transposed: Bs[n][k]

    const int tid  = threadIdx.x;
    const int m0   = blockIdx.x * BM;
    const int n0   = blockIdx.y * BN;
    const int lane = tid & 63;
    const int wid  = tid >> 6;
    const int wm   = (wid >> 1) * 64;
    const int wn   = (wid & 1) * 64;
    const int lr   = lane & 15;
    const int lk   = (lane >> 4) * 8;

    const int ar = tid >> 1,  ac = (tid & 1) * 16;   // A staging: 2 thr/row, 16 cols each
    const int bk = tid >> 3,  bn = (tid & 7) * 16;   // B staging: 8 thr/k-row, 16 cols

    f32x4 acc[4][4] = {};

    for (int k0 = 0; k0 < DIM; k0 += BK) {
        __syncthreads();
        // ---- stage A: x fp32 -> f16 LDS
        {
            const float* src = X + (size_t)(m0 + ar) * DIM + k0 + ac;
            float4 q0 = *(const float4*)(src + 0);
            float4 q1 = *(const float4*)(src + 4);
            float4 q2 = *(const float4*)(src + 8);
            float4 q3 = *(const float4*)(src + 12);
            f16x8 p0, p1;
            p0[0] = (_Float16)q0.x; p0[1] = (_Float16)q0.y;
            p0[2] = (_Float16)q0.z; p0[3] = (_Float16)q0.w;
            p0[4] = (_Float16)q1.x; p0[5] = (_Float16)q1.y;
            p0[6] = (_Float16)q1.z; p0[7] = (_Float16)q1.w;
            p1[0] = (_Float16)q2.x; p1[1] = (_Float16)q2.y;
            p1[2] = (_Float16)q2.z; p1[3] = (_Float16)q2.w;
            p1[4] = (_Float16)q3.x; p1[5] = (_Float16)q3.y;
            p1[6] = (_Float16)q3.z; p1[7] = (_Float16)q3.w;
            *(f16x8*)&As[ar][ac]     = p0;
            *(f16x8*)&As[ar][ac + 8] = p1;
        }
        // ---- stage B: W_x fp32 -> f16 LDS, transposed
        {
            const float* src = Wx + (size_t)(k0 + bk) * DIM + n0 + bn;
            float4 q0 = *(const float4*)(src + 0);
            float4 q1 = *(const float4*)(src + 4);
            float4 q2 = *(const float4*)(src + 8);
            float4 q3 = *(const float4*)(src + 12);
            float vv[16];
            *(float4*)&vv[0]  = q0; *(float4*)&vv[4]  = q1;
            *(float4*)&vv[8]  = q2; *(float4*)&vv[12] = q3;
            #pragma unroll
            for (int i = 0; i < 16; ++i) Bs[bn + i][bk] = (_Float16)vv[i];
        }
        __syncthreads();
        // ---- MFMA
        f16x8 a[4], bb[4];
        #pragma unroll
        for (int f = 0; f < 4; ++f) a[f]  = *(const f16x8*)&As[wm + f * 16 + lr][lk];
        #pragma unroll
        for (int f = 0; f < 4; ++f) bb[f] = *(const f16x8*)&Bs[wn + f * 16 + lr][lk];
        #pragma unroll
        for (int i = 0; i < 4; ++i)
            #pragma unroll
            for (int j = 0; j < 4; ++j)
                acc[i][j] = __builtin_amdgcn_mfma_f32_16x16x32_f16(
                    a[i], bb[j], acc[i][j], 0, 0, 0);
    }

    // ---- epilogue: C/D layout col = lane&15, row = (lane>>4)*4 + reg
    #pragma unroll
    for (int i = 0; i < 4; ++i) {
        #pragma unroll
        for (int j = 0; j < 4; ++j) {
            const int col = n0 + wn + j * 16 + lr;
            const float bv = bias[col];
            #pragma unroll
            for (int r = 0; r < 4; ++r) {
                const int row = m0 + wm + i * 16 + (lane >> 4) * 4 + r;
                __builtin_nontemporal_store(acc[i][j][r] + bv,
                                            out + (size_t)row * DIM + col);
            }
        }
    }
}

// ---------------------------------------------------------------------------
// Kernel 3: the sequential scan. One workgroup per batch row (sync-free across
// wgs). 1024 threads, thread j owns output column j. h kept in LDS as f16;
// per step: z = xW[t,b,j] + sum_k h[k]*Wh[k,j] via v_dot2_f32_f16 (f32 accum),
// h_new = tanh(z) written to hs[t] and h_all[t+1] (overwriting the xW slot).
// ---------------------------------------------------------------------------
__global__ __launch_bounds__(1024) void elman_rec(
    const float* __restrict__ h0,
    const _Float16* __restrict__ Wh2,
    float* __restrict__ hs,      // [T][B][D]
    float* __restrict__ h_all)   // [T+1][B][D]; [1:] pre-filled with xW
{
    const int b = blockIdx.x;
    const int j = threadIdx.x;
    __shared__ alignas(16) _Float16 hbuf[DIM];

    const float h0v = h0[(size_t)b * DIM + j];
    h_all[(size_t)b * DIM + j] = h0v;     // h_all[0] = h0
    hbuf[j] = (_Float16)h0v;
    __syncthreads();

    const uint4* wq = (const uint4*)Wh2 + j;     // wq[kb*DIM] = 8 halves, k=8kb..8kb+7, col j
    const uint4* hq = (const uint4*)hbuf;

    for (int t = 0; t < T_STEPS; ++t) {
        const size_t xo = ((size_t)(t + 1) * BATCH + b) * DIM + j;
        float z = __builtin_nontemporal_load(h_all + xo);   // xW[t,b,j]

        #pragma unroll 8
        for (int kb = 0; kb < DIM / 8; ++kb) {
            const uint4 w  = wq[(size_t)kb * DIM];
            const uint4 h4 = hq[kb];
            z = fdot2(h4.x, w.x, z);
            z = fdot2(h4.y, w.y, z);
            z = fdot2(h4.z, w.z, z);
            z = fdot2(h4.w, w.w, z);
        }

        // tanh(z) = 1 - 2/(e^{2z}+1): NaN-free for |z| large
        const float e  = __expf(2.0f * z);
        const float hn = 1.0f - 2.0f / (e + 1.0f);

        __builtin_nontemporal_store(hn, hs + (size_t)t * (BATCH * DIM) + (size_t)b * DIM + j);
        __builtin_nontemporal_store(hn, h_all + xo);

        __syncthreads();               // all dots done reading hbuf
        hbuf[j] = (_Float16)hn;
        __syncthreads();               // new h visible
    }
}

extern "C" void kernel_launch(void* const* d_in, const int* in_sizes, int n_in,
                              void* d_out, int out_size, void* d_ws, size_t ws_size,
                              hipStream_t stream) {
    const float* x    = (const float*)d_in[0];   // [T][B][D]
    const float* h0   = (const float*)d_in[1];   // [B][D]
    const float* Wx   = (const float*)d_in[2];   // [D][D]
    const float* Wh   = (const float*)d_in[3];   // [D][D]
    const float* bias = (const float*)d_in[4];   // [D]

    float* hs    = (float*)d_out;
    float* h_all = hs + (size_t)T_STEPS * BATCH * DIM;

    _Float16* Wh2 = (_Float16*)d_ws;             // 2 MB

    // 1) repack W_h to f16 dot2-friendly layout
    conv_wh<<<(DIM * DIM) / 256, 256, 0, stream>>>(Wh, Wh2);

    // 2) xW = x @ W_x + b  -> h_all[1:]
    dim3 g((T_STEPS * BATCH) / BM, DIM / BN);
    gemm_xw<<<g, 256, 0, stream>>>(x, Wx, bias, h_all + (size_t)BATCH * DIM);

    // 3) sequential scan, one wg per batch row
    elman_rec<<<BATCH, 1024, 0, stream>>>(h0, Wh2, hs, h_all);
}